// Round 5
// baseline (3491.883 us; speedup 1.0000x reference)
//
#include <hip/hip_runtime.h>
#include <stdint.h>

#define B_   128
#define T_   256
#define IN_  512
#define H_   1024
#define NG_  4096   // 4*H (gate-interleaved rows)
#define KC_  1536   // IN+H
#define OUT_ 512
#define NBLK 256    // 8 groups x 32 blocks
#define NTHR 512

typedef __bf16 bf16x8 __attribute__((ext_vector_type(8)));
typedef float  f32x4  __attribute__((ext_vector_type(4)));

__device__ __forceinline__ ushort f2bf(float f) {
    union { float f; uint32_t u; } v; v.f = f;
    uint32_t u = v.u;
    return (ushort)((u + 0x7FFFu + ((u >> 16) & 1u)) >> 16);  // RNE
}

__device__ __forceinline__ f32x4 mfma16(bf16x8 a, bf16x8 b, f32x4 c) {
    return __builtin_amdgcn_mfma_f32_16x16x32_bf16(a, b, c, 0, 0, 0);
}

__device__ __forceinline__ float sigf(float x) {
    return 1.f / (1.f + __expf(-x));
}

// ---------------- prep kernels ----------------

__global__ void prep_w(const float* __restrict__ Wf, const float* __restrict__ Wi,
                       const float* __restrict__ Wc, const float* __restrict__ Wo,
                       ushort* __restrict__ Wcat) {
    int row = blockIdx.x;            // 0..4095 (= 4*j+g)
    int j = row >> 2, g = row & 3;
    const float* W = (g == 0) ? Wf : (g == 1) ? Wi : (g == 2) ? Wc : Wo;
    for (int k = threadIdx.x; k < KC_; k += 256)
        Wcat[(size_t)row * KC_ + k] = f2bf(W[(size_t)j * KC_ + k]);
}

__global__ void prep_bias(const float* __restrict__ bf_, const float* __restrict__ bi_,
                          const float* __restrict__ bc_, const float* __restrict__ bo_,
                          float* __restrict__ bias) {
    int idx = blockIdx.x * 256 + threadIdx.x;  // 16 blocks -> 4096
    int j = idx >> 2, g = idx & 3;
    const float* b = (g == 0) ? bf_ : (g == 1) ? bi_ : (g == 2) ? bc_ : bo_;
    bias[idx] = b[j];
}

__global__ void prep_wout(const float* __restrict__ W, ushort* __restrict__ Wb) {
    int row = blockIdx.x;  // 512
    for (int k = threadIdx.x; k < H_; k += 256)
        Wb[(size_t)row * H_ + k] = f2bf(W[(size_t)row * H_ + k]);
}

__global__ void prep_x(const float* __restrict__ x, ushort* __restrict__ xT) {
    int bid = blockIdx.x;            // t*128 + b
    int t = bid >> 7, b = bid & 127;
    const float* src = x  + ((size_t)b * T_ + t) * IN_;
    ushort*      dst = xT + ((size_t)t * B_ + b) * IN_;
    for (int k = threadIdx.x; k < IN_; k += 256) dst[k] = f2bf(src[k]);
}

__global__ void prep_zero(ushort* __restrict__ hs0, unsigned int* __restrict__ flags) {
    int idx = blockIdx.x * 256 + threadIdx.x;  // 512*256 = 131072 = B_*H_
    hs0[idx] = 0;
    if (idx < NBLK) flags[idx] = 0u;
}

// ---------------- persistent LSTM kernel ----------------
// 256 blocks x 512 threads. Group = bx&7 (8 groups, XCD-affine), sub = bx>>3
// (32 blocks/group). Group g owns batch rows [g*16,+16); block sub owns gate
// cols [sub*128,+128). Each wave wv owns 16 gate cols (nv = wv) over the FULL
// K=1536: breg[48] = 192 VGPRs, PINNED via asm so the allocator cannot
// rematerialize the loads inside the t-loop (round-3 failure mode: VGPR=128,
// 100 MB/step W re-streamed from L3). No cross-wave reduction needed; the
// gate epilogue is a quad-lane shfl_xor exchange, c-state quad-redundant in
// VGPRs. x-part of K (16 chunks) is staged+computed BEFORE the group barrier
// poll (x_t is barrier-independent) to hide barrier latency.

__launch_bounds__(NTHR, 1)
__global__ void lstm_persist(const ushort* __restrict__ xT,
                             const ushort* __restrict__ Wcat,
                             const float* __restrict__ bias,
                             ushort* __restrict__ hs,
                             unsigned int* flags)
{
    __shared__ ushort As[16 * 1536];        // 48 KB  A tile, ^(row&15) swizzled

    const int tid  = threadIdx.x;
    const int lane = tid & 63;
    const int wv   = tid >> 6;        // 0..7 = n-subtile (16 cols)
    const int bx   = blockIdx.x;
    const int grp  = bx & 7;          // group (XCD-affine under bx%8 round-robin)
    const int sub  = bx >> 3;         // 0..31 within group
    const int nbase = sub * 128;      // block's gate-col base
    const int rbase = grp * 16;       // group's batch-row base

    const int colg  = nbase + wv * 16 + (lane & 15);  // this lane's gate column
    const int g     = lane & 3;                       // gate id (f,i,c~,o)
    const int unitg = colg >> 2;                      // global hidden unit

    // ---- persistent W fragments: breg[r] covers k = r*32 (full K) ----
    bf16x8 breg[48];
#pragma unroll
    for (int r = 0; r < 48; ++r)
        breg[r] = *(const bf16x8*)(Wcat + (size_t)colg * KC_ + r * 32 + (lane >> 4) * 8);
    // pin: asm-volatile results cannot be rematerialized -> stays in VGPRs
#pragma unroll
    for (int r = 0; r < 48; ++r) {
        f32x4 tmp = __builtin_bit_cast(f32x4, breg[r]);
        asm volatile("" : "+v"(tmp));
        breg[r] = __builtin_bit_cast(bf16x8, tmp);
    }

    const float biasv = bias[colg];
    float creg4[4] = {0.f, 0.f, 0.f, 0.f};   // c for rows (lane>>4)*4+q, own unit

    const int srow = tid >> 5;        // staging row 0..15
    const int scol = tid & 31;        // staging 16B segment within pass
    const int arow = lane & 15;       // A-frag row

    for (int t = 0; t < T_; ++t) {
        // ---- stage x-part (barrier-independent) ----
        const ushort* xTt = xT + ((size_t)t * B_ + rbase) * IN_;
        uint4 vx0 = *(const uint4*)(xTt + (size_t)srow * IN_ + scol * 8);
        uint4 vx1 = *(const uint4*)(xTt + (size_t)srow * IN_ + (32 + scol) * 8);
        *(uint4*)&As[srow * 1536 + ((scol)      ^ (srow & 15)) * 8] = vx0;
        *(uint4*)&As[srow * 1536 + ((32 + scol) ^ (srow & 15)) * 8] = vx1;
        __syncthreads();

        // ---- x-part MFMAs (k < 512) while other blocks may still be behind ----
        f32x4 accs[4];
#pragma unroll
        for (int j = 0; j < 4; ++j) accs[j] = (f32x4){0.f, 0.f, 0.f, 0.f};
#pragma unroll
        for (int r = 0; r < 16; ++r) {
            const int s = r * 4 + (lane >> 4);
            bf16x8 a = *(const bf16x8*)&As[arow * 1536 + (s ^ (arow & 15)) * 8];
            accs[r & 3] = mfma16(a, breg[r], accs[r & 3]);
        }

        // ---- group barrier: wait for all 32 blocks to publish h_t ----
        if (t > 0 && wv == 0) {
            const bool active = lane < 32;
            const unsigned int* fp = flags + (lane & 31) * 8 + grp;
            while (1) {
                unsigned v = active
                    ? __hip_atomic_load(fp, __ATOMIC_RELAXED, __HIP_MEMORY_SCOPE_AGENT)
                    : ~0u;
                if (__ballot(active && v < (unsigned)t) == 0ull) break;
                __builtin_amdgcn_s_sleep(1);
            }
            (void)__hip_atomic_load(flags + grp, __ATOMIC_ACQUIRE,
                                    __HIP_MEMORY_SCOPE_AGENT);  // cache invalidate
        }
        __syncthreads();

        // ---- stage h-part ----
        const ushort* ht = hs + ((size_t)t * B_ + rbase) * H_;
        uint4 vh[4];
#pragma unroll
        for (int p = 0; p < 4; ++p)
            vh[p] = *(const uint4*)(ht + (size_t)srow * H_ + (p * 32 + scol) * 8);
#pragma unroll
        for (int p = 0; p < 4; ++p) {
            const int s = 64 + p * 32 + scol;
            *(uint4*)&As[srow * 1536 + (s ^ (srow & 15)) * 8] = vh[p];
        }
        __syncthreads();

        // ---- h-part MFMAs (k >= 512) ----
#pragma unroll
        for (int r = 16; r < 48; ++r) {
            const int s = r * 4 + (lane >> 4);
            bf16x8 a = *(const bf16x8*)&As[arow * 1536 + (s ^ (arow & 15)) * 8];
            accs[r & 3] = mfma16(a, breg[r], accs[r & 3]);
        }
        f32x4 acc = (accs[0] + accs[1]) + (accs[2] + accs[3]);

        // ---- gate epilogue: quad-lane exchange, no LDS ----
        ushort* hout = hs + ((size_t)(t + 1) * B_ + rbase) * H_;
#pragma unroll
        for (int q = 0; q < 4; ++q) {
            float v = acc[q] + biasv;
            float a0 = (g == 2) ? tanhf(v) : sigf(v);   // own gate activated
            float a1 = __shfl_xor(a0, 1);
            float a2 = __shfl_xor(a0, 2);
            float a3 = __shfl_xor(a1, 2);               // lane^3
            float vf = (g == 0) ? a0 : (g == 1) ? a1 : (g == 2) ? a2 : a3;
            float vi = (g == 0) ? a1 : (g == 1) ? a0 : (g == 2) ? a3 : a2;
            float vc = (g == 0) ? a2 : (g == 1) ? a3 : (g == 2) ? a0 : a1;
            float vo = (g == 0) ? a3 : (g == 1) ? a2 : (g == 2) ? a1 : a0;
            float cn = vf * creg4[q] + vi * vc;
            creg4[q] = cn;
            if (g == 0) {
                const int m = (lane >> 4) * 4 + q;
                hout[(size_t)m * H_ + unitg] = f2bf(vo * tanhf(cn));
            }
        }
        __syncthreads();   // drain h stores (vmcnt0) before release
        if (tid == 0)
            __hip_atomic_store(flags + bx, (unsigned)(t + 1), __ATOMIC_RELEASE,
                               __HIP_MEMORY_SCOPE_AGENT);
    }
}

// ---------------- output projection GEMM ----------------

__launch_bounds__(256, 2)
__global__ void out_gemm(const ushort* __restrict__ hsflat,
                         const ushort* __restrict__ Wout,
                         const float* __restrict__ bout,
                         float* __restrict__ out)
{
    __shared__ ushort As2[128 * 64];
    __shared__ ushort Bs2[64 * 64];
    const int tid  = threadIdx.x;
    const int lane = tid & 63;
    const int wave = tid >> 6;
    const int wm = (wave >> 1) * 64;
    const int wn = (wave & 1) * 32;
    const int mbase = (blockIdx.x >> 3) * 128;
    const int nbase = (blockIdx.x & 7) * 64;

    f32x4 acc[4][2];
#pragma unroll
    for (int i = 0; i < 4; i++)
#pragma unroll
        for (int j = 0; j < 2; j++) acc[i][j] = (f32x4){0.f, 0.f, 0.f, 0.f};

    for (int kc = 0; kc < H_ / 64; ++kc) {
        const int k0 = kc * 64;
        __syncthreads();
#pragma unroll
        for (int it = 0; it < 4; ++it) {
            int g = it * 256 + tid;
            int row = g >> 3;
            int seg = g & 7;
            uint4 v = *(const uint4*)(hsflat + (size_t)(mbase + row) * H_ + k0 + seg * 8);
            int dstg = seg ^ (row & 7);
            *(uint4*)&As2[row * 64 + dstg * 8] = v;
        }
#pragma unroll
        for (int it = 0; it < 2; ++it) {
            int g = it * 256 + tid;
            int row = g >> 3;
            int seg = g & 7;
            uint4 v = *(const uint4*)(Wout + (size_t)(nbase + row) * H_ + k0 + seg * 8);
            int dstg = seg ^ (row & 7);
            *(uint4*)&Bs2[row * 64 + dstg * 8] = v;
        }
        __syncthreads();
#pragma unroll
        for (int ks = 0; ks < 2; ++ks) {
            const int kg = ks * 4 + (lane >> 4);
            bf16x8 af[4], bfr[2];
#pragma unroll
            for (int mi = 0; mi < 4; ++mi) {
                int row = wm + mi * 16 + (lane & 15);
                int gi = kg ^ (row & 7);
                af[mi] = *(const bf16x8*)&As2[row * 64 + gi * 8];
            }
#pragma unroll
            for (int ni = 0; ni < 2; ++ni) {
                int row = wn + ni * 16 + (lane & 15);
                int gi = kg ^ (row & 7);
                bfr[ni] = *(const bf16x8*)&Bs2[row * 64 + gi * 8];
            }
#pragma unroll
            for (int mi = 0; mi < 4; ++mi)
#pragma unroll
                for (int ni = 0; ni < 2; ++ni)
                    acc[mi][ni] = mfma16(af[mi], bfr[ni], acc[mi][ni]);
        }
    }

#pragma unroll
    for (int mi = 0; mi < 4; ++mi) {
#pragma unroll
        for (int ni = 0; ni < 2; ++ni) {
            int col = nbase + wn + ni * 16 + (lane & 15);
            float bv = bout[col];
#pragma unroll
            for (int q = 0; q < 4; ++q) {
                int rt = mbase + wm + mi * 16 + (lane >> 4) * 4 + q;
                int b = rt & 127, tt = rt >> 7;
                out[((size_t)b * T_ + tt) * OUT_ + col] = acc[mi][ni][q] + bv;
            }
        }
    }
}

// ---------------- launcher ----------------

extern "C" void kernel_launch(void* const* d_in, const int* in_sizes, int n_in,
                              void* d_out, int out_size, void* d_ws, size_t ws_size,
                              hipStream_t stream)
{
    const float* x    = (const float*)d_in[0];
    const float* Wf   = (const float*)d_in[1];
    const float* bf_  = (const float*)d_in[2];
    const float* Wi   = (const float*)d_in[3];
    const float* bi_  = (const float*)d_in[4];
    const float* Wc   = (const float*)d_in[5];
    const float* bc_  = (const float*)d_in[6];
    const float* Wo   = (const float*)d_in[7];
    const float* bo_  = (const float*)d_in[8];
    const float* Wout = (const float*)d_in[9];
    const float* bout = (const float*)d_in[10];
    float* out = (float*)d_out;

    char* ws = (char*)d_ws;
    size_t off = 0;
    auto alloc = [&](size_t bytes) {
        char* p = ws + off;
        off += (bytes + 255) & ~(size_t)255;
        return p;
    };
    ushort* xT   = (ushort*)alloc((size_t)T_ * B_ * IN_ * 2);       // 33.6 MB
    ushort* Wcat = (ushort*)alloc((size_t)NG_ * KC_ * 2);           // 12.6 MB
    float*  bias = (float*) alloc((size_t)NG_ * 4);
    ushort* Wob  = (ushort*)alloc((size_t)OUT_ * H_ * 2);           // 1 MB
    ushort* hs   = (ushort*)alloc((size_t)(T_ + 1) * B_ * H_ * 2);  // 67.4 MB
    unsigned int* flags = (unsigned int*)alloc((size_t)NBLK * 4);

    hipLaunchKernelGGL(prep_w,    dim3(NG_), dim3(256), 0, stream, Wf, Wi, Wc, Wo, Wcat);
    hipLaunchKernelGGL(prep_bias, dim3(16),  dim3(256), 0, stream, bf_, bi_, bc_, bo_, bias);
    hipLaunchKernelGGL(prep_wout, dim3(OUT_),dim3(256), 0, stream, Wout, Wob);
    hipLaunchKernelGGL(prep_x,    dim3(T_ * B_), dim3(256), 0, stream, x, xT);
    hipLaunchKernelGGL(prep_zero, dim3(512), dim3(256), 0, stream, hs, flags);

    hipLaunchKernelGGL(lstm_persist, dim3(NBLK), dim3(NTHR), 0, stream,
                       xT, Wcat, bias, hs, flags);

    hipLaunchKernelGGL(out_gemm, dim3(2048), dim3(256), 0, stream,
                       hs + (size_t)B_ * H_, Wob, bout, out);
}

// Round 6
// 1841.859 us; speedup vs baseline: 1.8958x; 1.8958x over previous
//
#include <hip/hip_runtime.h>
#include <stdint.h>

#define B_   128
#define T_   256
#define IN_  512
#define H_   1024
#define NG_  4096   // 4*H (gate-interleaved rows)
#define KC_  1536   // IN+H
#define OUT_ 512
#define NBLK 256    // 8 groups x 32 blocks
#define NTHR 512

typedef __bf16 bf16x8 __attribute__((ext_vector_type(8)));
typedef float  f32x4  __attribute__((ext_vector_type(4)));

__device__ __forceinline__ ushort f2bf(float f) {
    union { float f; uint32_t u; } v; v.f = f;
    uint32_t u = v.u;
    return (ushort)((u + 0x7FFFu + ((u >> 16) & 1u)) >> 16);  // RNE
}

__device__ __forceinline__ f32x4 mfma16(bf16x8 a, bf16x8 b, f32x4 c) {
    return __builtin_amdgcn_mfma_f32_16x16x32_bf16(a, b, c, 0, 0, 0);
}

__device__ __forceinline__ float sigf(float x) {
    return 1.f / (1.f + __expf(-x));
}

// ---------------- prep kernels ----------------

__global__ void prep_w(const float* __restrict__ Wf, const float* __restrict__ Wi,
                       const float* __restrict__ Wc, const float* __restrict__ Wo,
                       ushort* __restrict__ Wcat) {
    int row = blockIdx.x;            // 0..4095 (= 4*j+g)
    int j = row >> 2, g = row & 3;
    const float* W = (g == 0) ? Wf : (g == 1) ? Wi : (g == 2) ? Wc : Wo;
    for (int k = threadIdx.x; k < KC_; k += 256)
        Wcat[(size_t)row * KC_ + k] = f2bf(W[(size_t)j * KC_ + k]);
}

__global__ void prep_bias(const float* __restrict__ bf_, const float* __restrict__ bi_,
                          const float* __restrict__ bc_, const float* __restrict__ bo_,
                          float* __restrict__ bias) {
    int idx = blockIdx.x * 256 + threadIdx.x;  // 16 blocks -> 4096
    int j = idx >> 2, g = idx & 3;
    const float* b = (g == 0) ? bf_ : (g == 1) ? bi_ : (g == 2) ? bc_ : bo_;
    bias[idx] = b[j];
}

__global__ void prep_wout(const float* __restrict__ W, ushort* __restrict__ Wb) {
    int row = blockIdx.x;  // 512
    for (int k = threadIdx.x; k < H_; k += 256)
        Wb[(size_t)row * H_ + k] = f2bf(W[(size_t)row * H_ + k]);
}

__global__ void prep_x(const float* __restrict__ x, ushort* __restrict__ xT) {
    int bid = blockIdx.x;            // t*128 + b
    int t = bid >> 7, b = bid & 127;
    const float* src = x  + ((size_t)b * T_ + t) * IN_;
    ushort*      dst = xT + ((size_t)t * B_ + b) * IN_;
    for (int k = threadIdx.x; k < IN_; k += 256) dst[k] = f2bf(src[k]);
}

__global__ void prep_zero(ushort* __restrict__ hs0, unsigned int* __restrict__ flags) {
    int idx = blockIdx.x * 256 + threadIdx.x;  // 512*256 = 131072 = B_*H_
    hs0[idx] = 0;
    if (idx < NBLK) flags[idx] = 0u;
}

// ---------------- persistent LSTM kernel ----------------
// 256 blocks x 512 threads, 1 block/CU (LDS padded >80KB on purpose: with
// occupancy LDS-capped, the register allocator grants up to 256 VGPRs, so
// breg[48] (192 VGPRs of W) stays truly resident — rounds 3/4 failed because
// at <=66KB LDS the allocator chose 128 VGPRs for 2-blocks/CU occupancy and
// rematerialized/spilled W every step).
// Coherence: NO acquire/release fences (they invalidate L2 every step and
// evict W/x). h moves through the LLC-coherent path only: relaxed agent-scope
// atomic dword stores/loads (sc0+sc1: bypass L1/L2, coherent at Infinity
// Cache). Ordering: __syncthreads drains vmcnt(0) (h stores LLC-visible)
// before the relaxed flag store; readers' h loads are control-dependent on
// the polled flag value. W/x use normal cached loads and stay hot.

__launch_bounds__(NTHR, 1)
__global__ void lstm_persist(const ushort* __restrict__ xT,
                             const ushort* __restrict__ Wcat,
                             const float* __restrict__ bias,
                             ushort* __restrict__ hs,
                             unsigned int* flags)
{
    __shared__ ushort As[16 * 1536];   // 48 KB A tile, ^(row&15) swizzled (0 conflicts, r4-verified)
    __shared__ ushort pad_[20480];     // 40 KB occupancy limiter -> 1 block/CU

    const int tid  = threadIdx.x;
    const int lane = tid & 63;
    const int wv   = tid >> 6;        // 0..7 = n-subtile (16 cols)
    const int bx   = blockIdx.x;
    const int grp  = bx & 7;          // group (XCD-affine under bx%8 round-robin)
    const int sub  = bx >> 3;         // 0..31 within group
    const int nbase = sub * 128;      // block's gate-col base
    const int rbase = grp * 16;       // group's batch-row base

    pad_[tid] = 0;                    // keep pad_ allocated

    const int colg  = nbase + wv * 16 + (lane & 15);  // this lane's gate column
    const int g     = lane & 3;                       // gate id (f,i,c~,o)
    const int unitg = colg >> 2;                      // global hidden unit

    // ---- persistent W fragments: breg[r] covers k = r*32 (full K) ----
    bf16x8 breg[48];
#pragma unroll
    for (int r = 0; r < 48; ++r)
        breg[r] = *(const bf16x8*)(Wcat + (size_t)colg * KC_ + r * 32 + (lane >> 4) * 8);
#pragma unroll
    for (int r = 0; r < 48; ++r) {    // pin against rematerialization
        f32x4 tmp = __builtin_bit_cast(f32x4, breg[r]);
        asm volatile("" : "+v"(tmp));
        breg[r] = __builtin_bit_cast(bf16x8, tmp);
    }

    const float biasv = bias[colg];
    float creg4[4] = {0.f, 0.f, 0.f, 0.f};   // c for rows (lane>>4)*4+q, own unit

    const int srow = tid >> 5;        // staging row 0..15
    const int sc32 = tid & 31;        // staging lane-within-row
    const int arow = lane & 15;       // A-frag row

    for (int t = 0; t < T_; ++t) {
        // ---- stage x-part (normal cached loads; barrier-independent) ----
        const ushort* xTt = xT + ((size_t)t * B_ + rbase) * IN_;
        {
            uint4 v0 = *(const uint4*)(xTt + (size_t)srow * IN_ + sc32 * 8);
            uint4 v1 = *(const uint4*)(xTt + (size_t)srow * IN_ + (32 + sc32) * 8);
            *(uint4*)&As[srow * 1536 + ((sc32)      ^ (srow & 15)) * 8] = v0;
            *(uint4*)&As[srow * 1536 + ((32 + sc32) ^ (srow & 15)) * 8] = v1;
        }
        __syncthreads();

        // ---- x-part MFMAs (k < 512) before the group barrier ----
        f32x4 accs[2];
        accs[0] = (f32x4){0.f, 0.f, 0.f, 0.f};
        accs[1] = (f32x4){0.f, 0.f, 0.f, 0.f};
#pragma unroll
        for (int r = 0; r < 16; ++r) {
            const int s = r * 4 + (lane >> 4);
            bf16x8 a = *(const bf16x8*)&As[arow * 1536 + (s ^ (arow & 15)) * 8];
            accs[r & 1] = mfma16(a, breg[r], accs[r & 1]);
        }

        // ---- group barrier: poll 32 flags (relaxed agent = LLC-fresh) ----
        if (t > 0 && wv == 0) {
            const bool active = lane < 32;
            const unsigned int* fp = flags + (lane & 31) * 8 + grp;
            while (1) {
                unsigned v = active
                    ? __hip_atomic_load(fp, __ATOMIC_RELAXED, __HIP_MEMORY_SCOPE_AGENT)
                    : ~0u;
                if (__ballot(active && v < (unsigned)t) == 0ull) break;
                __builtin_amdgcn_s_sleep(1);
            }
        }
        __syncthreads();

        // ---- stage h-part via LLC-coherent dword loads ----
        const unsigned int* hrow =
            (const unsigned int*)(hs + ((size_t)t * B_ + rbase + srow) * H_);
#pragma unroll
        for (int jb = 0; jb < 2; ++jb) {
            unsigned int hv[8];
#pragma unroll
            for (int j = 0; j < 8; ++j)
                hv[j] = __hip_atomic_load(hrow + (jb * 8 + j) * 32 + sc32,
                                          __ATOMIC_RELAXED, __HIP_MEMORY_SCOPE_AGENT);
#pragma unroll
            for (int j = 0; j < 8; ++j) {
                const int jj = jb * 8 + j;
                const int z = jj * 8 + (sc32 >> 2);           // seg-in-h-region 0..127
                *(unsigned int*)&As[srow * 1536 + ((64 + z) ^ (srow & 15)) * 8
                                    + (sc32 & 3) * 2] = hv[j];
            }
        }
        __syncthreads();

        // ---- h-part MFMAs (k >= 512) ----
#pragma unroll
        for (int r = 16; r < 48; ++r) {
            const int s = r * 4 + (lane >> 4);
            bf16x8 a = *(const bf16x8*)&As[arow * 1536 + (s ^ (arow & 15)) * 8];
            accs[r & 1] = mfma16(a, breg[r], accs[r & 1]);
        }
        f32x4 acc = accs[0] + accs[1];

        // ---- gate epilogue: quad-lane exchange, h stored as LLC dwords ----
        unsigned int* hout = (unsigned int*)(hs + ((size_t)(t + 1) * B_ + rbase) * H_);
#pragma unroll
        for (int q = 0; q < 4; ++q) {
            float v = acc[q] + biasv;
            float a0 = (g == 2) ? tanhf(v) : sigf(v);   // own gate activated
            float a1 = __shfl_xor(a0, 1);
            float a2 = __shfl_xor(a0, 2);
            float a3 = __shfl_xor(a1, 2);               // lane^3
            float vf = (g == 0) ? a0 : (g == 1) ? a1 : (g == 2) ? a2 : a3;
            float vi = (g == 0) ? a1 : (g == 1) ? a0 : (g == 2) ? a3 : a2;
            float vc = (g == 0) ? a2 : (g == 1) ? a3 : (g == 2) ? a0 : a1;
            float vo = (g == 0) ? a3 : (g == 1) ? a2 : (g == 2) ? a1 : a0;
            float cn = vf * creg4[q] + vi * vc;
            creg4[q] = cn;
            unsigned int hu = (unsigned int)f2bf(vo * tanhf(cn));
            unsigned int hp = (unsigned int)__shfl_xor((int)hu, 4);  // partner unit+1
            if ((lane & 7) == 0) {
                const int m = (lane >> 4) * 4 + q;
                __hip_atomic_store(hout + m * 512 + (unitg >> 1), hu | (hp << 16),
                                   __ATOMIC_RELAXED, __HIP_MEMORY_SCOPE_AGENT);
            }
        }
        __syncthreads();   // drains vmcnt(0): all sc1 h stores LLC-visible
        if (tid == 0)
            __hip_atomic_store(flags + bx, (unsigned)(t + 1), __ATOMIC_RELAXED,
                               __HIP_MEMORY_SCOPE_AGENT);
    }
}

// ---------------- output projection GEMM ----------------

__launch_bounds__(256, 2)
__global__ void out_gemm(const ushort* __restrict__ hsflat,
                         const ushort* __restrict__ Wout,
                         const float* __restrict__ bout,
                         float* __restrict__ out)
{
    __shared__ ushort As2[128 * 64];
    __shared__ ushort Bs2[64 * 64];
    const int tid  = threadIdx.x;
    const int lane = tid & 63;
    const int wave = tid >> 6;
    const int wm = (wave >> 1) * 64;
    const int wn = (wave & 1) * 32;
    const int mbase = (blockIdx.x >> 3) * 128;
    const int nbase = (blockIdx.x & 7) * 64;

    f32x4 acc[4][2];
#pragma unroll
    for (int i = 0; i < 4; i++)
#pragma unroll
        for (int j = 0; j < 2; j++) acc[i][j] = (f32x4){0.f, 0.f, 0.f, 0.f};

    for (int kc = 0; kc < H_ / 64; ++kc) {
        const int k0 = kc * 64;
        __syncthreads();
#pragma unroll
        for (int it = 0; it < 4; ++it) {
            int g = it * 256 + tid;
            int row = g >> 3;
            int seg = g & 7;
            uint4 v = *(const uint4*)(hsflat + (size_t)(mbase + row) * H_ + k0 + seg * 8);
            int dstg = seg ^ (row & 7);
            *(uint4*)&As2[row * 64 + dstg * 8] = v;
        }
#pragma unroll
        for (int it = 0; it < 2; ++it) {
            int g = it * 256 + tid;
            int row = g >> 3;
            int seg = g & 7;
            uint4 v = *(const uint4*)(Wout + (size_t)(nbase + row) * H_ + k0 + seg * 8);
            int dstg = seg ^ (row & 7);
            *(uint4*)&Bs2[row * 64 + dstg * 8] = v;
        }
        __syncthreads();
#pragma unroll
        for (int ks = 0; ks < 2; ++ks) {
            const int kg = ks * 4 + (lane >> 4);
            bf16x8 af[4], bfr[2];
#pragma unroll
            for (int mi = 0; mi < 4; ++mi) {
                int row = wm + mi * 16 + (lane & 15);
                int gi = kg ^ (row & 7);
                af[mi] = *(const bf16x8*)&As2[row * 64 + gi * 8];
            }
#pragma unroll
            for (int ni = 0; ni < 2; ++ni) {
                int row = wn + ni * 16 + (lane & 15);
                int gi = kg ^ (row & 7);
                bfr[ni] = *(const bf16x8*)&Bs2[row * 64 + gi * 8];
            }
#pragma unroll
            for (int mi = 0; mi < 4; ++mi)
#pragma unroll
                for (int ni = 0; ni < 2; ++ni)
                    acc[mi][ni] = mfma16(af[mi], bfr[ni], acc[mi][ni]);
        }
    }

#pragma unroll
    for (int mi = 0; mi < 4; ++mi) {
#pragma unroll
        for (int ni = 0; ni < 2; ++ni) {
            int col = nbase + wn + ni * 16 + (lane & 15);
            float bv = bout[col];
#pragma unroll
            for (int q = 0; q < 4; ++q) {
                int rt = mbase + wm + mi * 16 + (lane >> 4) * 4 + q;
                int b = rt & 127, tt = rt >> 7;
                out[((size_t)b * T_ + tt) * OUT_ + col] = acc[mi][ni][q] + bv;
            }
        }
    }
}

// ---------------- launcher ----------------

extern "C" void kernel_launch(void* const* d_in, const int* in_sizes, int n_in,
                              void* d_out, int out_size, void* d_ws, size_t ws_size,
                              hipStream_t stream)
{
    const float* x    = (const float*)d_in[0];
    const float* Wf   = (const float*)d_in[1];
    const float* bf_  = (const float*)d_in[2];
    const float* Wi   = (const float*)d_in[3];
    const float* bi_  = (const float*)d_in[4];
    const float* Wc   = (const float*)d_in[5];
    const float* bc_  = (const float*)d_in[6];
    const float* Wo   = (const float*)d_in[7];
    const float* bo_  = (const float*)d_in[8];
    const float* Wout = (const float*)d_in[9];
    const float* bout = (const float*)d_in[10];
    float* out = (float*)d_out;

    char* ws = (char*)d_ws;
    size_t off = 0;
    auto alloc = [&](size_t bytes) {
        char* p = ws + off;
        off += (bytes + 255) & ~(size_t)255;
        return p;
    };
    ushort* xT   = (ushort*)alloc((size_t)T_ * B_ * IN_ * 2);       // 33.6 MB
    ushort* Wcat = (ushort*)alloc((size_t)NG_ * KC_ * 2);           // 12.6 MB
    float*  bias = (float*) alloc((size_t)NG_ * 4);
    ushort* Wob  = (ushort*)alloc((size_t)OUT_ * H_ * 2);           // 1 MB
    ushort* hs   = (ushort*)alloc((size_t)(T_ + 1) * B_ * H_ * 2);  // 67.4 MB
    unsigned int* flags = (unsigned int*)alloc((size_t)NBLK * 4);

    hipLaunchKernelGGL(prep_w,    dim3(NG_), dim3(256), 0, stream, Wf, Wi, Wc, Wo, Wcat);
    hipLaunchKernelGGL(prep_bias, dim3(16),  dim3(256), 0, stream, bf_, bi_, bc_, bo_, bias);
    hipLaunchKernelGGL(prep_wout, dim3(OUT_),dim3(256), 0, stream, Wout, Wob);
    hipLaunchKernelGGL(prep_x,    dim3(T_ * B_), dim3(256), 0, stream, x, xT);
    hipLaunchKernelGGL(prep_zero, dim3(512), dim3(256), 0, stream, hs, flags);

    hipLaunchKernelGGL(lstm_persist, dim3(NBLK), dim3(NTHR), 0, stream,
                       xT, Wcat, bias, hs, flags);

    hipLaunchKernelGGL(out_gemm, dim3(2048), dim3(256), 0, stream,
                       hs + (size_t)B_ * H_, Wob, bout, out);
}

// Round 7
// 1792.321 us; speedup vs baseline: 1.9482x; 1.0276x over previous
//
#include <hip/hip_runtime.h>
#include <stdint.h>

#define B_   128
#define T_   256
#define IN_  512
#define H_   1024
#define NG_  4096   // 4*H (gate-interleaved rows)
#define KC_  1536   // IN+H
#define OUT_ 512
#define NBLK 256    // 8 groups x 32 blocks
#define NTHR 512

typedef __bf16 bf16x8 __attribute__((ext_vector_type(8)));
typedef float  f32x4  __attribute__((ext_vector_type(4)));

__device__ __forceinline__ ushort f2bf(float f) {
    union { float f; uint32_t u; } v; v.f = f;
    uint32_t u = v.u;
    return (ushort)((u + 0x7FFFu + ((u >> 16) & 1u)) >> 16);  // RNE
}

__device__ __forceinline__ f32x4 mfma16(bf16x8 a, bf16x8 b, f32x4 c) {
    return __builtin_amdgcn_mfma_f32_16x16x32_bf16(a, b, c, 0, 0, 0);
}

__device__ __forceinline__ float sigf(float x) {
    return 1.f / (1.f + __expf(-x));
}

// ---------------- prep kernels ----------------

__global__ void prep_w(const float* __restrict__ Wf, const float* __restrict__ Wi,
                       const float* __restrict__ Wc, const float* __restrict__ Wo,
                       ushort* __restrict__ Wcat) {
    int row = blockIdx.x;            // 0..4095 (= 4*j+g)
    int j = row >> 2, g = row & 3;
    const float* W = (g == 0) ? Wf : (g == 1) ? Wi : (g == 2) ? Wc : Wo;
    for (int k = threadIdx.x; k < KC_; k += 256)
        Wcat[(size_t)row * KC_ + k] = f2bf(W[(size_t)j * KC_ + k]);
}

__global__ void prep_bias(const float* __restrict__ bf_, const float* __restrict__ bi_,
                          const float* __restrict__ bc_, const float* __restrict__ bo_,
                          float* __restrict__ bias) {
    int idx = blockIdx.x * 256 + threadIdx.x;  // 16 blocks -> 4096
    int j = idx >> 2, g = idx & 3;
    const float* b = (g == 0) ? bf_ : (g == 1) ? bi_ : (g == 2) ? bc_ : bo_;
    bias[idx] = b[j];
}

__global__ void prep_wout(const float* __restrict__ W, ushort* __restrict__ Wb) {
    int row = blockIdx.x;  // 512
    for (int k = threadIdx.x; k < H_; k += 256)
        Wb[(size_t)row * H_ + k] = f2bf(W[(size_t)row * H_ + k]);
}

__global__ void prep_x(const float* __restrict__ x, ushort* __restrict__ xT) {
    int bid = blockIdx.x;            // t*128 + b
    int t = bid >> 7, b = bid & 127;
    const float* src = x  + ((size_t)b * T_ + t) * IN_;
    ushort*      dst = xT + ((size_t)t * B_ + b) * IN_;
    for (int k = threadIdx.x; k < IN_; k += 256) dst[k] = f2bf(src[k]);
}

__global__ void prep_zero(ushort* __restrict__ hs0, unsigned int* __restrict__ flags) {
    int idx = blockIdx.x * 256 + threadIdx.x;  // 512*256 = 131072 = B_*H_
    hs0[idx] = 0;
    if (idx < NBLK) flags[idx] = 0u;
}

// ---------------- persistent LSTM kernel ----------------
// 256 blocks x 512 threads. Group = bx&7 (8 groups, XCD-affine), sub = bx>>3
// (32 blocks/group). Group g owns batch rows [g*16,+16); block sub owns gate
// cols [sub*128,+128); wave wv owns 16 cols over full K=1536: breg[48] =
// 192 VGPRs of W, pinned. Register story (r3-r5 lesson): the allocator
// targets the LDS-allowed occupancy (48KB -> 2 blk/CU -> 4 waves/EU -> 128
// VGPRs) and remats/spills anything above it; LDS padding failed because
// dead stores got eliminated. Fix: amdgpu_waves_per_eu(2,2) — min 2 caps at
// 256 VGPRs (= what 8 waves/block needs), max 2 removes the incentive to
// compress to 128. Coherence (r5, kept): no acquire/release fences; h moves
// via relaxed agent-scope atomics (LLC-coherent, L1/L2 bypass); ordering =
// syncthreads vmcnt-drain before flag store, reader control-dep on flag.

__global__ void
__attribute__((amdgpu_flat_work_group_size(NTHR, NTHR), amdgpu_waves_per_eu(2, 2)))
lstm_persist(const ushort* __restrict__ xT,
             const ushort* __restrict__ Wcat,
             const float* __restrict__ bias,
             ushort* __restrict__ hs,
             unsigned int* flags)
{
    __shared__ ushort As[16 * 1536];   // 48 KB A tile, ^(row&15) swizzled (0 conflicts)

    const int tid  = threadIdx.x;
    const int lane = tid & 63;
    const int wv   = tid >> 6;        // 0..7 = n-subtile (16 cols)
    const int bx   = blockIdx.x;
    const int grp  = bx & 7;          // group (XCD-affine under bx%8 round-robin)
    const int sub  = bx >> 3;         // 0..31 within group
    const int nbase = sub * 128;      // block's gate-col base
    const int rbase = grp * 16;       // group's batch-row base

    const int colg  = nbase + wv * 16 + (lane & 15);  // this lane's gate column
    const int g     = lane & 3;                       // gate id (f,i,c~,o)
    const int unitg = colg >> 2;                      // global hidden unit

    // ---- persistent W fragments: breg[r] covers k = r*32 (full K) ----
    bf16x8 breg[48];
#pragma unroll
    for (int r = 0; r < 48; ++r)
        breg[r] = *(const bf16x8*)(Wcat + (size_t)colg * KC_ + r * 32 + (lane >> 4) * 8);
#pragma unroll
    for (int r = 0; r < 48; ++r) {    // pin against rematerialization
        f32x4 tmp = __builtin_bit_cast(f32x4, breg[r]);
        asm volatile("" : "+v"(tmp));
        breg[r] = __builtin_bit_cast(bf16x8, tmp);
    }

    const float biasv = bias[colg];
    float creg4[4] = {0.f, 0.f, 0.f, 0.f};   // c for rows (lane>>4)*4+q, own unit

    const int srow = tid >> 5;        // staging row 0..15
    const int sc32 = tid & 31;        // staging lane-within-row
    const int arow = lane & 15;       // A-frag row

    for (int t = 0; t < T_; ++t) {
        // ---- stage x-part (normal cached loads; barrier-independent) ----
        const ushort* xTt = xT + ((size_t)t * B_ + rbase) * IN_;
        {
            uint4 v0 = *(const uint4*)(xTt + (size_t)srow * IN_ + sc32 * 8);
            uint4 v1 = *(const uint4*)(xTt + (size_t)srow * IN_ + (32 + sc32) * 8);
            *(uint4*)&As[srow * 1536 + ((sc32)      ^ (srow & 15)) * 8] = v0;
            *(uint4*)&As[srow * 1536 + ((32 + sc32) ^ (srow & 15)) * 8] = v1;
        }
        __syncthreads();

        // ---- x-part MFMAs (k < 512) before the group barrier ----
        f32x4 accs[2];
        accs[0] = (f32x4){0.f, 0.f, 0.f, 0.f};
        accs[1] = (f32x4){0.f, 0.f, 0.f, 0.f};
#pragma unroll
        for (int r = 0; r < 16; ++r) {
            const int s = r * 4 + (lane >> 4);
            bf16x8 a = *(const bf16x8*)&As[arow * 1536 + (s ^ (arow & 15)) * 8];
            accs[r & 1] = mfma16(a, breg[r], accs[r & 1]);
        }

        // ---- group barrier: poll 32 flags (relaxed agent = LLC-fresh) ----
        if (t > 0 && wv == 0) {
            const bool active = lane < 32;
            const unsigned int* fp = flags + (lane & 31) * 8 + grp;
            while (1) {
                unsigned v = active
                    ? __hip_atomic_load(fp, __ATOMIC_RELAXED, __HIP_MEMORY_SCOPE_AGENT)
                    : ~0u;
                if (__ballot(active && v < (unsigned)t) == 0ull) break;
                __builtin_amdgcn_s_sleep(1);
            }
        }
        __syncthreads();

        // ---- stage h-part via LLC-coherent dword loads ----
        const unsigned int* hrow =
            (const unsigned int*)(hs + ((size_t)t * B_ + rbase + srow) * H_);
#pragma unroll
        for (int jb = 0; jb < 2; ++jb) {
            unsigned int hv[8];
#pragma unroll
            for (int j = 0; j < 8; ++j)
                hv[j] = __hip_atomic_load(hrow + (jb * 8 + j) * 32 + sc32,
                                          __ATOMIC_RELAXED, __HIP_MEMORY_SCOPE_AGENT);
#pragma unroll
            for (int j = 0; j < 8; ++j) {
                const int jj = jb * 8 + j;
                const int z = jj * 8 + (sc32 >> 2);           // seg-in-h-region 0..127
                *(unsigned int*)&As[srow * 1536 + ((64 + z) ^ (srow & 15)) * 8
                                    + (sc32 & 3) * 2] = hv[j];
            }
        }
        __syncthreads();

        // ---- h-part MFMAs (k >= 512) ----
#pragma unroll
        for (int r = 16; r < 48; ++r) {
            const int s = r * 4 + (lane >> 4);
            bf16x8 a = *(const bf16x8*)&As[arow * 1536 + (s ^ (arow & 15)) * 8];
            accs[r & 1] = mfma16(a, breg[r], accs[r & 1]);
        }
        f32x4 acc = accs[0] + accs[1];

        // ---- gate epilogue: quad-lane exchange, h stored as LLC dwords ----
        unsigned int* hout = (unsigned int*)(hs + ((size_t)(t + 1) * B_ + rbase) * H_);
#pragma unroll
        for (int q = 0; q < 4; ++q) {
            float v = acc[q] + biasv;
            float a0 = (g == 2) ? tanhf(v) : sigf(v);   // own gate activated
            float a1 = __shfl_xor(a0, 1);
            float a2 = __shfl_xor(a0, 2);
            float a3 = __shfl_xor(a1, 2);               // lane^3
            float vf = (g == 0) ? a0 : (g == 1) ? a1 : (g == 2) ? a2 : a3;
            float vi = (g == 0) ? a1 : (g == 1) ? a0 : (g == 2) ? a3 : a2;
            float vc = (g == 0) ? a2 : (g == 1) ? a3 : (g == 2) ? a0 : a1;
            float vo = (g == 0) ? a3 : (g == 1) ? a2 : (g == 2) ? a1 : a0;
            float cn = vf * creg4[q] + vi * vc;
            creg4[q] = cn;
            unsigned int hu = (unsigned int)f2bf(vo * tanhf(cn));
            unsigned int hp = (unsigned int)__shfl_xor((int)hu, 4);  // partner unit+1
            if ((lane & 7) == 0) {
                const int m = (lane >> 4) * 4 + q;
                __hip_atomic_store(hout + m * 512 + (unitg >> 1), hu | (hp << 16),
                                   __ATOMIC_RELAXED, __HIP_MEMORY_SCOPE_AGENT);
            }
        }
        __syncthreads();   // drains vmcnt(0): all sc1 h stores LLC-visible
        if (tid == 0)
            __hip_atomic_store(flags + bx, (unsigned)(t + 1), __ATOMIC_RELAXED,
                               __HIP_MEMORY_SCOPE_AGENT);
    }
}

// ---------------- output projection GEMM ----------------

__launch_bounds__(256, 2)
__global__ void out_gemm(const ushort* __restrict__ hsflat,
                         const ushort* __restrict__ Wout,
                         const float* __restrict__ bout,
                         float* __restrict__ out)
{
    __shared__ ushort As2[128 * 64];
    __shared__ ushort Bs2[64 * 64];
    const int tid  = threadIdx.x;
    const int lane = tid & 63;
    const int wave = tid >> 6;
    const int wm = (wave >> 1) * 64;
    const int wn = (wave & 1) * 32;
    const int mbase = (blockIdx.x >> 3) * 128;
    const int nbase = (blockIdx.x & 7) * 64;

    f32x4 acc[4][2];
#pragma unroll
    for (int i = 0; i < 4; i++)
#pragma unroll
        for (int j = 0; j < 2; j++) acc[i][j] = (f32x4){0.f, 0.f, 0.f, 0.f};

    for (int kc = 0; kc < H_ / 64; ++kc) {
        const int k0 = kc * 64;
        __syncthreads();
#pragma unroll
        for (int it = 0; it < 4; ++it) {
            int g = it * 256 + tid;
            int row = g >> 3;
            int seg = g & 7;
            uint4 v = *(const uint4*)(hsflat + (size_t)(mbase + row) * H_ + k0 + seg * 8);
            int dstg = seg ^ (row & 7);
            *(uint4*)&As2[row * 64 + dstg * 8] = v;
        }
#pragma unroll
        for (int it = 0; it < 2; ++it) {
            int g = it * 256 + tid;
            int row = g >> 3;
            int seg = g & 7;
            uint4 v = *(const uint4*)(Wout + (size_t)(nbase + row) * H_ + k0 + seg * 8);
            int dstg = seg ^ (row & 7);
            *(uint4*)&Bs2[row * 64 + dstg * 8] = v;
        }
        __syncthreads();
#pragma unroll
        for (int ks = 0; ks < 2; ++ks) {
            const int kg = ks * 4 + (lane >> 4);
            bf16x8 af[4], bfr[2];
#pragma unroll
            for (int mi = 0; mi < 4; ++mi) {
                int row = wm + mi * 16 + (lane & 15);
                int gi = kg ^ (row & 7);
                af[mi] = *(const bf16x8*)&As2[row * 64 + gi * 8];
            }
#pragma unroll
            for (int ni = 0; ni < 2; ++ni) {
                int row = wn + ni * 16 + (lane & 15);
                int gi = kg ^ (row & 7);
                bfr[ni] = *(const bf16x8*)&Bs2[row * 64 + gi * 8];
            }
#pragma unroll
            for (int mi = 0; mi < 4; ++mi)
#pragma unroll
                for (int ni = 0; ni < 2; ++ni)
                    acc[mi][ni] = mfma16(af[mi], bfr[ni], acc[mi][ni]);
        }
    }

#pragma unroll
    for (int mi = 0; mi < 4; ++mi) {
#pragma unroll
        for (int ni = 0; ni < 2; ++ni) {
            int col = nbase + wn + ni * 16 + (lane & 15);
            float bv = bout[col];
#pragma unroll
            for (int q = 0; q < 4; ++q) {
                int rt = mbase + wm + mi * 16 + (lane >> 4) * 4 + q;
                int b = rt & 127, tt = rt >> 7;
                out[((size_t)b * T_ + tt) * OUT_ + col] = acc[mi][ni][q] + bv;
            }
        }
    }
}

// ---------------- launcher ----------------

extern "C" void kernel_launch(void* const* d_in, const int* in_sizes, int n_in,
                              void* d_out, int out_size, void* d_ws, size_t ws_size,
                              hipStream_t stream)
{
    const float* x    = (const float*)d_in[0];
    const float* Wf   = (const float*)d_in[1];
    const float* bf_  = (const float*)d_in[2];
    const float* Wi   = (const float*)d_in[3];
    const float* bi_  = (const float*)d_in[4];
    const float* Wc   = (const float*)d_in[5];
    const float* bc_  = (const float*)d_in[6];
    const float* Wo   = (const float*)d_in[7];
    const float* bo_  = (const float*)d_in[8];
    const float* Wout = (const float*)d_in[9];
    const float* bout = (const float*)d_in[10];
    float* out = (float*)d_out;

    char* ws = (char*)d_ws;
    size_t off = 0;
    auto alloc = [&](size_t bytes) {
        char* p = ws + off;
        off += (bytes + 255) & ~(size_t)255;
        return p;
    };
    ushort* xT   = (ushort*)alloc((size_t)T_ * B_ * IN_ * 2);       // 33.6 MB
    ushort* Wcat = (ushort*)alloc((size_t)NG_ * KC_ * 2);           // 12.6 MB
    float*  bias = (float*) alloc((size_t)NG_ * 4);
    ushort* Wob  = (ushort*)alloc((size_t)OUT_ * H_ * 2);           // 1 MB
    ushort* hs   = (ushort*)alloc((size_t)(T_ + 1) * B_ * H_ * 2);  // 67.4 MB
    unsigned int* flags = (unsigned int*)alloc((size_t)NBLK * 4);

    hipLaunchKernelGGL(prep_w,    dim3(NG_), dim3(256), 0, stream, Wf, Wi, Wc, Wo, Wcat);
    hipLaunchKernelGGL(prep_bias, dim3(16),  dim3(256), 0, stream, bf_, bi_, bc_, bo_, bias);
    hipLaunchKernelGGL(prep_wout, dim3(OUT_),dim3(256), 0, stream, Wout, Wob);
    hipLaunchKernelGGL(prep_x,    dim3(T_ * B_), dim3(256), 0, stream, x, xT);
    hipLaunchKernelGGL(prep_zero, dim3(512), dim3(256), 0, stream, hs, flags);

    hipLaunchKernelGGL(lstm_persist, dim3(NBLK), dim3(NTHR), 0, stream,
                       xT, Wcat, bias, hs, flags);

    hipLaunchKernelGGL(out_gemm, dim3(2048), dim3(256), 0, stream,
                       hs + (size_t)B_ * H_, Wob, bout, out);
}